// Round 12
// baseline (160.153 us; speedup 1.0000x reference)
//
#include <hip/hip_runtime.h>
#include <cstdint>
#include <cstddef>
#include <math.h>

typedef unsigned short u16;

#define S_LEN 2048
#define EMB   1024
#define HID   1024
#define NB    4

using bf16x8 = __attribute__((ext_vector_type(8))) __bf16;
using f32x4  = __attribute__((ext_vector_type(4))) float;

// ---------- helpers ----------

__device__ __forceinline__ u16 f2bf(float f) {
  union { float f; uint32_t u; } c; c.f = f;
  uint32_t u = c.u;
  uint32_t r = (u + 0x7fffu + ((u >> 16) & 1u)) >> 16;  // RNE
  return (u16)r;
}

__device__ __forceinline__ void gld_lds16(const u16* g, u16* l) {
  auto gp = (const __attribute__((address_space(1))) uint32_t*)(uintptr_t)(const void*)g;
  auto lp = (__attribute__((address_space(3))) uint32_t*)(uintptr_t)(void*)l;
  __builtin_amdgcn_global_load_lds(gp, lp, 16, 0, 0);
}

// ---------- fp32 -> bf16 convert: single fused launch ----------
// layout: [x: nx4 float4] [wq: nw4] [wk: nw4] [wv: nw4]; nw4 is a power of 2.

__global__ void cvt_all(const float* __restrict__ x,  const float* __restrict__ wq,
                        const float* __restrict__ wk, const float* __restrict__ wv,
                        u16* __restrict__ xb, u16* __restrict__ wb, int nx4, int nw4lg2) {
  const int nw4 = 1 << nw4lg2;
  const int total = nx4 + 3 * nw4;
  int i = blockIdx.x * blockDim.x + threadIdx.x;
  const int stride = gridDim.x * blockDim.x;
  for (; i < total; i += stride) {
    const float* src; u16* dst; int j;
    if (i < nx4) { src = x; dst = xb; j = i; }
    else {
      const int k = i - nx4;
      const int wsel = k >> nw4lg2;
      j = k & (nw4 - 1);
      src = (wsel == 0) ? wq : (wsel == 1) ? wk : wv;
      dst = wb + ((size_t)wsel << (nw4lg2 + 2));
    }
    float4 v = reinterpret_cast<const float4*>(src)[j];
    reinterpret_cast<ushort4*>(dst)[j] =
      make_ushort4(f2bf(v.x), f2bf(v.y), f2bf(v.z), f2bf(v.w));
  }
}

// ============================================================================
// gemmT: 128x128 tile, BK=64 (two 32-col halves), FOUR waves (2M x 2N,
// per-wave 64x64, acc[4][4]) -> 32 FLOP/LDS-byte vs R11's 21.3.
// LDS 2 bufs x 32KB = 64 KB -> 2 blocks/CU. R11-PROVEN phase protocol:
//   { 8 ds_read own frags; stage ONE half (4 gld_lds) for the phase 2 ahead;
//     vmcnt(4); barrier; 16 MFMA }   -- 1 barrier/phase, vmcnt never drains.
// LDS map (u16): buf d*16384 + { A.k0:0, A.k1:4096, B.k0:8192, B.k1:12288 }.
// Phase map (iter i): P0(d0,k0) P1(d0,k1) P2(d1,k0) P3(d1,k1);
//   stage: P0->(2i+1).k0@d1 P1->(2i+1).k1@d1 P2->(2i+2).k0@d0 P3->(2i+2).k1@d0
// Ledger (same as R11): region staged at P was last read at P-2; that read is
// lgkm-drained before MFMA(P-2), which precedes barrier(P-1), which precedes
// stage(P). Involution chunk swizzle (0-conflict): chunk ^= row-bit3 << 1,
// applied at global source + ds_read.
// EPI 2: f32 *scale + causal mask, triangular grid (scores; K=1024)
// EPI 4: fused QKV routing + bias (proj; grid 24x64 = 1536 = 3 exact rounds)
// ============================================================================

template<int EPI>
__global__ __launch_bounds__(256, 2)
void gemmT(const u16* __restrict__ A, const u16* __restrict__ Bw, void* __restrict__ Cv,
           const float* __restrict__ b0, const float* __restrict__ b1,
           const float* __restrict__ b2, u16* __restrict__ VT,
           int N, long sA, long sB, long sC, float scale)
{
  constexpr int K = 1024;
  constexpr int NTILE = K / 64;        // 16
  const int z = blockIdx.z;
  A  += (long)z * sA;
  Bw += (long)z * sB;

  __shared__ __align__(16) u16 smem[32768];   // 64 KB

  const int tid = threadIdx.x;
  const int l   = tid & 63;
  const int w   = tid >> 6;            // 0..3
  const int wr  = w >> 1;              // 0..1 (64-row)
  const int wc  = w & 1;               // 0..1 (64-col)

  int bm, bn;
  if constexpr (EPI == 2) {
    // T1 swizzle (gridDim.x = 136 = 8*17) then lower-triangular decode
    const int x0 = blockIdx.x;
    const int x  = (x0 & 7) * ((int)gridDim.x >> 3) + (x0 >> 3);
    int bi = (int)((sqrtf(8.0f * (float)x + 1.0f) - 1.0f) * 0.5f);
    while ((bi + 1) * (bi + 2) / 2 <= x) ++bi;
    while (bi * (bi + 1) / 2 > x) --bi;
    bm = bi * 128;
    bn = (x - bi * (bi + 1) / 2) * 128;
  } else {
    // T1 swizzle over 2D grid (nwg = 24*64 = 1536, %8 == 0)
    const int nwg = gridDim.x * gridDim.y;
    const int lin = blockIdx.y * gridDim.x + blockIdx.x;
    const int sw  = (lin & 7) * (nwg >> 3) + (lin >> 3);
    bm = (sw / gridDim.x) * 128;
    bn = (sw % gridDim.x) * 128;
  }

  // ---- staging lane geometry (pre-swizzled source chunk) ----
  // instr k of a half covers rows k*64 + w*16 + (l>>2); row bit3 = (l>>5)&1
  const int arow = w * 16 + (l >> 2);                 // 0..63
  const int acs  = (l & 3) ^ (((l >> 5) & 1) << 1);   // chunk ^ row-bit3 flip
  const u16* gbA  = A  + (long)(bm + arow) * K + acs * 8;
  const u16* gbA2 = gbA + 64L * K;
  const u16* gbB  = Bw + (long)(bn + arow) * K + acs * 8;
  const u16* gbB2 = gbB + 64L * K;

#define STGH(t, s, dbase)                                                       \
  do {                                                                          \
    const long _o = (long)(t) * 64 + (s) * 32;                                  \
    gld_lds16(gbA  + _o, smem + (dbase) + (s) * 4096 +        w * 512);         \
    gld_lds16(gbA2 + _o, smem + (dbase) + (s) * 4096 + 2048 + w * 512);         \
    gld_lds16(gbB  + _o, smem + (dbase) + 8192 + (s) * 4096 +        w * 512);  \
    gld_lds16(gbB2 + _o, smem + (dbase) + 8192 + (s) * 4096 + 2048 + w * 512);  \
  } while (0)

  // ---- fragment ds_read offsets (region-local, u16 units), swizzled ----
  const int lr  = l & 15;
  const int kg  = l >> 4;
  const int kgp = kg ^ (((lr >> 3) & 1) << 1);
  int aoff[4], boff[4];
#pragma unroll
  for (int m = 0; m < 4; ++m) aoff[m] = (wr * 64 + m * 16 + lr) * 32 + kgp * 8;
#pragma unroll
  for (int n = 0; n < 4; ++n) boff[n] = (wc * 64 + n * 16 + lr) * 32 + kgp * 8;

  f32x4 acc[4][4] = {};

  // ---- prologue: tile 0 both halves -> buf0; drain once ----
  STGH(0, 0, 0);
  STGH(0, 1, 0);
  asm volatile("s_waitcnt vmcnt(0)" ::: "memory");
  __builtin_amdgcn_s_barrier();
  asm volatile("" ::: "memory");

#define PHASE(d, s, STGSTMT)                                                    \
  do {                                                                          \
    const u16* hA = smem + (d) * 16384 + (s) * 4096;                            \
    const u16* hB = smem + (d) * 16384 + 8192 + (s) * 4096;                     \
    bf16x8 av[4], bv[4];                                                        \
    _Pragma("unroll")                                                           \
    for (int m_ = 0; m_ < 4; ++m_)                                              \
      av[m_] = *reinterpret_cast<const bf16x8*>(hA + aoff[m_]);                 \
    _Pragma("unroll")                                                           \
    for (int n_ = 0; n_ < 4; ++n_)                                              \
      bv[n_] = *reinterpret_cast<const bf16x8*>(hB + boff[n_]);                 \
    STGSTMT;                                                                    \
    asm volatile("s_waitcnt vmcnt(4)" ::: "memory");                            \
    __builtin_amdgcn_s_barrier();                                               \
    asm volatile("" ::: "memory");                                              \
    __builtin_amdgcn_s_setprio(1);                                              \
    _Pragma("unroll")                                                           \
    for (int m_ = 0; m_ < 4; ++m_)                                              \
      _Pragma("unroll")                                                         \
      for (int n_ = 0; n_ < 4; ++n_)                                            \
        acc[m_][n_] = __builtin_amdgcn_mfma_f32_16x16x32_bf16(                  \
            av[m_], bv[n_], acc[m_][n_], 0, 0, 0);                              \
    __builtin_amdgcn_s_setprio(0);                                              \
    asm volatile("" ::: "memory");                                              \
  } while (0)

#pragma unroll 1
  for (int i = 0; i < NTILE / 2; ++i) {
    const int t1 = 2 * i + 1;
    const int t2 = (2 * i + 2 < NTILE) ? 2 * i + 2 : NTILE - 1;
    PHASE(0, 0, STGH(t1, 0, 16384));
    PHASE(0, 1, STGH(t1, 1, 16384));
    PHASE(1, 0, STGH(t2, 0, 0));
    PHASE(1, 1, STGH(t2, 1, 0));
  }
#undef PHASE
#undef STGH

  // ---- epilogue: C map col=lane&15, row=(lane>>4)*4+q ----
  if constexpr (EPI == 2) {            // f32, scaled, causal mask (scores)
    float* C = (float*)Cv + (long)z * sC;
#pragma unroll
    for (int n = 0; n < 4; ++n) {
      const int col = bn + wc * 64 + n * 16 + lr;
#pragma unroll
      for (int m = 0; m < 4; ++m) {
        const int row0 = bm + wr * 64 + m * 16 + kg * 4;
#pragma unroll
        for (int q = 0; q < 4; ++q) {
          const int row = row0 + q;
          float v = acc[m][n][q] * scale;
          if (col > row) v = -1e30f;
          C[(long)row * N + col] = v;
        }
      }
    }
  } else {                             // EPI 4: fused QKV routing (proj)
    constexpr long M = (long)NB * S_LEN;
    const int sel = bn >> 10;          // 0=Q, 1=K, 2=V (block-uniform, 128 | 1024)
    const float* bias = (sel == 0) ? b0 : (sel == 1) ? b1 : b2;
    u16* QK = (u16*)Cv;
#pragma unroll
    for (int n = 0; n < 4; ++n) {
      const int col = bn + wc * 64 + n * 16 + lr;
      const int h   = col & (HID - 1);
      const float bbv = bias[h];
#pragma unroll
      for (int m = 0; m < 4; ++m) {
        const int row0 = bm + wr * 64 + m * 16 + kg * 4;
        if (sel < 2) {
          u16* dst = QK + (long)sel * M * HID + (long)row0 * HID + h;
#pragma unroll
          for (int q = 0; q < 4; ++q)
            dst[(long)q * HID] = f2bf(acc[m][n][q] + bbv);
        } else {
          const int b = row0 >> 11;
          const int s = row0 & (S_LEN - 1);
          ushort4 o = make_ushort4(f2bf(acc[m][n][0] + bbv), f2bf(acc[m][n][1] + bbv),
                                   f2bf(acc[m][n][2] + bbv), f2bf(acc[m][n][3] + bbv));
          *reinterpret_cast<ushort4*>(VT + ((long)b * HID + h) * S_LEN + s) = o;
        }
      }
    }
  }
}

// ============================================================================
// gemm_pv: load-balanced causal PV (R10-proven, unchanged).
// ============================================================================

__global__ __launch_bounds__(512, 2)
void gemm_pv(const u16* __restrict__ Pm, const u16* __restrict__ VTm, float* __restrict__ Cm)
{
  const int z = blockIdx.z;
  const u16* A = Pm  + (long)z * S_LEN * S_LEN;
  const u16* B = VTm + (long)z * HID * S_LEN;
  float*    Cz = Cm  + (long)z * S_LEN * HID;

  __shared__ __align__(16) u16 smem[32768];   // 64 KB

  const int tid = threadIdx.x;
  const int l   = tid & 63;
  const int w   = tid >> 6;
  const int wr  = w >> 2;              // 0..1 (64-row)
  const int wc  = w & 3;               // 0..3 (32-col)
  const int bn  = blockIdx.x * 128;
  const int pr  = blockIdx.y;          // 0..7

  const int lr  = l & 15;
  const int kg  = l >> 4;
  const int kgp = kg ^ (((lr >> 3) & 1) << 1);
  int aoff[4], boff[2];
#pragma unroll
  for (int m = 0; m < 4; ++m) aoff[m] = (wr * 64 + m * 16 + lr) * 32 + kgp * 8;
#pragma unroll
  for (int n = 0; n < 2; ++n) boff[n] = (wc * 32 + n * 16 + lr) * 32 + kgp * 8;

  const int arow = w * 16 + (l >> 2);                 // 0..127
  const int acs  = (l & 3) ^ (((l >> 5) & 1) << 1);

#pragma unroll 1
  for (int it = 0; it < 2; ++it) {
    const int bi = (it == 0) ? (15 - pr) : pr;        // long row-tile first
    const int bm = bi * 128;
    const int NTILE = (bi + 1) * 2;                   // even, >= 2

    const u16* gbA = A + (long)(bm + arow) * S_LEN + acs * 8;
    const u16* gbB = B + (long)(bn + arow) * S_LEN + acs * 8;

#define STGH(t, s, dbase)                                                       \
  do {                                                                          \
    const long _o = (long)(t) * 64 + (s) * 32;                                  \
    gld_lds16(gbA + _o, smem + (dbase) + (s) * 4096 + w * 512);                 \
    gld_lds16(gbB + _o, smem + (dbase) + 8192 + (s) * 4096 + w * 512);          \
  } while (0)

    if (it) {                          // all iter-1 LDS reads complete past here
      __builtin_amdgcn_s_barrier();
      asm volatile("" ::: "memory");
    }

    f32x4 acc[4][2] = {};

    // prologue: tile 0 both halves -> buf0; drain
    STGH(0, 0, 0);
    STGH(0, 1, 0);
    asm volatile("s_waitcnt vmcnt(0)" ::: "memory");
    __builtin_amdgcn_s_barrier();
    asm volatile("" ::: "memory");

#define PHASE(d, s, STGSTMT)                                                    \
  do {                                                                          \
    const u16* hA = smem + (d) * 16384 + (s) * 4096;                            \
    const u16* hB = smem + (d) * 16384 + 8192 + (s) * 4096;                     \
    bf16x8 av[4], bv[2];                                                        \
    _Pragma("unroll")                                                           \
    for (int m_ = 0; m_ < 4; ++m_)                                              \
      av[m_] = *reinterpret_cast<const bf16x8*>(hA + aoff[m_]);                 \
    _Pragma("unroll")                                                           \
    for (int n_ = 0; n_ < 2; ++n_)                                              \
      bv[n_] = *reinterpret_cast<const bf16x8*>(hB + boff[n_]);                 \
    STGSTMT;                                                                    \
    asm volatile("s_waitcnt vmcnt(2)" ::: "memory");                            \
    __builtin_amdgcn_s_barrier();                                               \
    asm volatile("" ::: "memory");                                              \
    __builtin_amdgcn_s_setprio(1);                                              \
    _Pragma("unroll")                                                           \
    for (int m_ = 0; m_ < 4; ++m_)                                              \
      _Pragma("unroll")                                                         \
      for (int n_ = 0; n_ < 2; ++n_)                                            \
        acc[m_][n_] = __builtin_amdgcn_mfma_f32_16x16x32_bf16(                  \
            av[m_], bv[n_], acc[m_][n_], 0, 0, 0);                              \
    __builtin_amdgcn_s_setprio(0);                                              \
    asm volatile("" ::: "memory");                                              \
  } while (0)

#pragma unroll 1
    for (int i = 0; i < NTILE / 2; ++i) {
      const int t1 = 2 * i + 1;
      const int t2 = (2 * i + 2 < NTILE) ? 2 * i + 2 : NTILE - 1;
      PHASE(0, 0, STGH(t1, 0, 16384));
      PHASE(0, 1, STGH(t1, 1, 16384));
      PHASE(1, 0, STGH(t2, 0, 0));
      PHASE(1, 1, STGH(t2, 1, 0));
    }
#undef PHASE
#undef STGH

    // epilogue: C map col=lane&15, row=(lane>>4)*4+q
#pragma unroll
    for (int n = 0; n < 2; ++n) {
      const int col = bn + wc * 32 + n * 16 + lr;
#pragma unroll
      for (int m = 0; m < 4; ++m) {
        const int row0 = bm + wr * 64 + m * 16 + kg * 4;
#pragma unroll
        for (int q = 0; q < 4; ++q)
          Cz[(long)(row0 + q) * HID + col] = acc[m][n][q];
      }
    }
  }
}

// ---------- causal row softmax: fp32 scores -> bf16 P (kend 128-aligned) ----------

__global__ __launch_bounds__(256)
void softmax_causal(const float* __restrict__ Sc, u16* __restrict__ P, long sS, long sP)
{
  const int row  = blockIdx.x;
  const int z    = blockIdx.y;
  const int kend = ((row >> 7) + 1) << 7;
  const float* srow = Sc + (long)z * sS + (long)row * S_LEN;
  u16*        prow = P  + (long)z * sP + (long)row * S_LEN;
  const int t = threadIdx.x;
  const int lane = t & 63, wave = t >> 6;

  const bool p0 = (4 * t) < kend;
  const bool p1 = (1024 + 4 * t) < kend;

  float4 v0 = make_float4(-1e30f, -1e30f, -1e30f, -1e30f);
  float4 v1 = v0;
  if (p0) v0 = reinterpret_cast<const float4*>(srow)[t];
  if (p1) v1 = reinterpret_cast<const float4*>(srow)[t + 256];

  float mx = fmaxf(fmaxf(fmaxf(v0.x, v0.y), fmaxf(v0.z, v0.w)),
                   fmaxf(fmaxf(v1.x, v1.y), fmaxf(v1.z, v1.w)));

  __shared__ float red[8];
#pragma unroll
  for (int off = 32; off; off >>= 1) mx = fmaxf(mx, __shfl_down(mx, off));
  if (lane == 0) red[wave] = mx;
  __syncthreads();
  mx = fmaxf(fmaxf(red[0], red[1]), fmaxf(red[2], red[3]));

  float e[8];
  e[0] = __expf(v0.x - mx); e[1] = __expf(v0.y - mx);
  e[2] = __expf(v0.z - mx); e[3] = __expf(v0.w - mx);
  e[4] = __expf(v1.x - mx); e[5] = __expf(v1.y - mx);
  e[6] = __expf(v1.z - mx); e[7] = __expf(v1.w - mx);

  float sm = ((e[0] + e[1]) + (e[2] + e[3])) + ((e[4] + e[5]) + (e[6] + e[7]));
#pragma unroll
  for (int off = 32; off; off >>= 1) sm += __shfl_down(sm, off);
  if (lane == 0) red[4 + wave] = sm;
  __syncthreads();
  sm = (red[4] + red[5]) + (red[6] + red[7]);

  const float inv = 1.0f / sm;
  if (p0)
    reinterpret_cast<ushort4*>(prow)[t] =
      make_ushort4(f2bf(e[0]*inv), f2bf(e[1]*inv), f2bf(e[2]*inv), f2bf(e[3]*inv));
  if (p1)
    reinterpret_cast<ushort4*>(prow)[t + 256] =
      make_ushort4(f2bf(e[4]*inv), f2bf(e[5]*inv), f2bf(e[6]*inv), f2bf(e[7]*inv));
}

// ---------- launch ----------

extern "C" void kernel_launch(void* const* d_in, const int* in_sizes, int n_in,
                              void* d_out, int out_size, void* d_ws, size_t ws_size,
                              hipStream_t stream)
{
  const float* x  = (const float*)d_in[0];
  const float* Wq = (const float*)d_in[1];
  const float* bq = (const float*)d_in[2];
  const float* Wk = (const float*)d_in[3];
  const float* bk = (const float*)d_in[4];
  const float* Wv = (const float*)d_in[5];
  const float* bv = (const float*)d_in[6];
  float* out = (float*)d_out;

  const long M = (long)NB * S_LEN;  // 8192

  u16* xb  = (u16*)d_ws;
  u16* wqb = xb  + M * EMB;         // wq/wk/wv contiguous -> fused [3072,1024]
  u16* Qb  = wqb + 3L * HID * EMB;  // Q then K contiguous
  u16* Kb  = Qb  + M * HID;
  u16* VT  = Kb  + M * HID;
  char* rest = (char*)(VT + M * HID);
  const size_t used  = (size_t)(rest - (char*)d_ws);
  const size_t ssz   = (size_t)S_LEN * S_LEN;
  const size_t need4 = used + (size_t)NB * ssz * 4 + (size_t)NB * ssz * 2;
  const int nb = (ws_size >= need4) ? NB : 1;
  float* scores = (float*)rest;
  u16*   P      = (u16*)(rest + (size_t)nb * ssz * 4);

  // fp32 -> bf16 (single fused launch; nw4 = 1024*1024/4 = 2^18)
  cvt_all<<<2048, 256, 0, stream>>>(x, Wq, Wk, Wv, xb, wqb, (int)(M * EMB / 4), 18);

  // fused QKV projection: 128x128 4-wave template, grid 1536 = 3 exact rounds
  gemmT<4><<<dim3(24, 64, 1), 256, 0, stream>>>(xb, wqb, Qb, bq, bk, bv, VT,
                                                3 * HID, 0, 0, 0, 1.0f);

  const float scale = 0.03125f;  // 1/sqrt(1024)
  const int TRI = 16 * 17 / 2;   // 136 lower-tri 128x128 blocks

  if (nb == NB) {
    dim3 gs(TRI, 1, NB);
    gemmT<2><<<gs, 256, 0, stream>>>(Qb, Kb, scores, nullptr, nullptr, nullptr, nullptr,
                                     S_LEN, (long)S_LEN * HID, (long)S_LEN * HID,
                                     (long)ssz, scale);
    softmax_causal<<<dim3(S_LEN, NB), 256, 0, stream>>>(scores, P, (long)ssz, (long)ssz);
    gemm_pv<<<dim3(8, 8, NB), 512, 0, stream>>>(P, VT, out);
  } else {
    for (int b = 0; b < NB; ++b) {
      const u16* Qbb = Qb + (long)b * S_LEN * HID;
      const u16* Kbb = Kb + (long)b * S_LEN * HID;
      const u16* VTb = VT + (long)b * HID * S_LEN;
      float* outb = out + (long)b * S_LEN * HID;
      dim3 gs(TRI, 1, 1);
      gemmT<2><<<gs, 256, 0, stream>>>(Qbb, Kbb, scores, nullptr, nullptr, nullptr, nullptr,
                                       S_LEN, 0, 0, 0, scale);
      softmax_causal<<<dim3(S_LEN, 1), 256, 0, stream>>>(scores, P, 0, 0);
      gemm_pv<<<dim3(8, 8, 1), 512, 0, stream>>>(P, VTb, outb);
    }
  }
}

// Round 13
// 157.880 us; speedup vs baseline: 1.0144x; 1.0144x over previous
//
#include <hip/hip_runtime.h>
#include <cstdint>
#include <cstddef>
#include <math.h>

typedef unsigned short u16;

#define S_LEN 2048
#define EMB   1024
#define HID   1024
#define NB    4

using bf16x8 = __attribute__((ext_vector_type(8))) __bf16;
using f32x4  = __attribute__((ext_vector_type(4))) float;

// ---------- helpers ----------

__device__ __forceinline__ u16 f2bf(float f) {
  union { float f; uint32_t u; } c; c.f = f;
  uint32_t u = c.u;
  uint32_t r = (u + 0x7fffu + ((u >> 16) & 1u)) >> 16;  // RNE
  return (u16)r;
}

__device__ __forceinline__ float bf2f(uint32_t hi16) {
  union { uint32_t u; float f; } c; c.u = hi16;
  return c.f;
}

__device__ __forceinline__ void gld_lds16(const u16* g, u16* l) {
  auto gp = (const __attribute__((address_space(1))) uint32_t*)(uintptr_t)(const void*)g;
  auto lp = (__attribute__((address_space(3))) uint32_t*)(uintptr_t)(void*)l;
  __builtin_amdgcn_global_load_lds(gp, lp, 16, 0, 0);
}

// ---------- fp32 -> bf16 convert: single fused launch ----------
// layout: [x: nx4 float4] [wq: nw4] [wk: nw4] [wv: nw4]; nw4 is a power of 2.

__global__ void cvt_all(const float* __restrict__ x,  const float* __restrict__ wq,
                        const float* __restrict__ wk, const float* __restrict__ wv,
                        u16* __restrict__ xb, u16* __restrict__ wb, int nx4, int nw4lg2) {
  const int nw4 = 1 << nw4lg2;
  const int total = nx4 + 3 * nw4;
  int i = blockIdx.x * blockDim.x + threadIdx.x;
  const int stride = gridDim.x * blockDim.x;
  for (; i < total; i += stride) {
    const float* src; u16* dst; int j;
    if (i < nx4) { src = x; dst = xb; j = i; }
    else {
      const int k = i - nx4;
      const int wsel = k >> nw4lg2;
      j = k & (nw4 - 1);
      src = (wsel == 0) ? wq : (wsel == 1) ? wk : wv;
      dst = wb + ((size_t)wsel << (nw4lg2 + 2));
    }
    float4 v = reinterpret_cast<const float4*>(src)[j];
    reinterpret_cast<ushort4*>(dst)[j] =
      make_ushort4(f2bf(v.x), f2bf(v.y), f2bf(v.z), f2bf(v.w));
  }
}

// ============================================================================
// gemmT: 128x128 tile, BK=64 (two 32-col halves), FOUR waves (2M x 2N,
// per-wave 64x64, acc[4][4]). R12-proven phase protocol:
//   { 8 ds_read own frags; stage ONE half (4 gld_lds) for the phase 2 ahead;
//     vmcnt(4); barrier; 16 MFMA }   -- 1 barrier/phase, vmcnt never drains.
// LDS 2 bufs x 32KB = 64 KB -> 2 blocks/CU.
// LDS map (u16): buf d*16384 + { A.k0:0, A.k1:4096, B.k0:8192, B.k1:12288 }.
// Involution chunk swizzle (0-conflict): chunk ^= row-bit3 << 1, applied at
// global source + ds_read.
// EPI 2: bf16 out, *scale + causal mask, triangular grid (scores; K=1024)
// EPI 4: fused QKV routing + bias (proj; grid 24x64 = 1536 = 3 exact rounds)
// ============================================================================

template<int EPI>
__global__ __launch_bounds__(256, 2)
void gemmT(const u16* __restrict__ A, const u16* __restrict__ Bw, void* __restrict__ Cv,
           const float* __restrict__ b0, const float* __restrict__ b1,
           const float* __restrict__ b2, u16* __restrict__ VT,
           int N, long sA, long sB, long sC, float scale)
{
  constexpr int K = 1024;
  constexpr int NTILE = K / 64;        // 16
  const int z = blockIdx.z;
  A  += (long)z * sA;
  Bw += (long)z * sB;

  __shared__ __align__(16) u16 smem[32768];   // 64 KB

  const int tid = threadIdx.x;
  const int l   = tid & 63;
  const int w   = tid >> 6;            // 0..3
  const int wr  = w >> 1;              // 0..1 (64-row)
  const int wc  = w & 1;               // 0..1 (64-col)

  int bm, bn;
  if constexpr (EPI == 2) {
    // T1 swizzle (gridDim.x = 136 = 8*17) then lower-triangular decode
    const int x0 = blockIdx.x;
    const int x  = (x0 & 7) * ((int)gridDim.x >> 3) + (x0 >> 3);
    int bi = (int)((sqrtf(8.0f * (float)x + 1.0f) - 1.0f) * 0.5f);
    while ((bi + 1) * (bi + 2) / 2 <= x) ++bi;
    while (bi * (bi + 1) / 2 > x) --bi;
    bm = bi * 128;
    bn = (x - bi * (bi + 1) / 2) * 128;
  } else {
    // T1 swizzle over 2D grid (nwg = 24*64 = 1536, %8 == 0)
    const int nwg = gridDim.x * gridDim.y;
    const int lin = blockIdx.y * gridDim.x + blockIdx.x;
    const int sw  = (lin & 7) * (nwg >> 3) + (lin >> 3);
    bm = (sw / gridDim.x) * 128;
    bn = (sw % gridDim.x) * 128;
  }

  // ---- staging lane geometry (pre-swizzled source chunk) ----
  const int arow = w * 16 + (l >> 2);                 // 0..63
  const int acs  = (l & 3) ^ (((l >> 5) & 1) << 1);   // chunk ^ row-bit3 flip
  const u16* gbA  = A  + (long)(bm + arow) * K + acs * 8;
  const u16* gbA2 = gbA + 64L * K;
  const u16* gbB  = Bw + (long)(bn + arow) * K + acs * 8;
  const u16* gbB2 = gbB + 64L * K;

#define STGH(t, s, dbase)                                                       \
  do {                                                                          \
    const long _o = (long)(t) * 64 + (s) * 32;                                  \
    gld_lds16(gbA  + _o, smem + (dbase) + (s) * 4096 +        w * 512);         \
    gld_lds16(gbA2 + _o, smem + (dbase) + (s) * 4096 + 2048 + w * 512);         \
    gld_lds16(gbB  + _o, smem + (dbase) + 8192 + (s) * 4096 +        w * 512);  \
    gld_lds16(gbB2 + _o, smem + (dbase) + 8192 + (s) * 4096 + 2048 + w * 512);  \
  } while (0)

  // ---- fragment ds_read offsets (region-local, u16 units), swizzled ----
  const int lr  = l & 15;
  const int kg  = l >> 4;
  const int kgp = kg ^ (((lr >> 3) & 1) << 1);
  int aoff[4], boff[4];
#pragma unroll
  for (int m = 0; m < 4; ++m) aoff[m] = (wr * 64 + m * 16 + lr) * 32 + kgp * 8;
#pragma unroll
  for (int n = 0; n < 4; ++n) boff[n] = (wc * 64 + n * 16 + lr) * 32 + kgp * 8;

  f32x4 acc[4][4] = {};

  // ---- prologue: tile 0 both halves -> buf0; drain once ----
  STGH(0, 0, 0);
  STGH(0, 1, 0);
  asm volatile("s_waitcnt vmcnt(0)" ::: "memory");
  __builtin_amdgcn_s_barrier();
  asm volatile("" ::: "memory");

#define PHASE(d, s, STGSTMT)                                                    \
  do {                                                                          \
    const u16* hA = smem + (d) * 16384 + (s) * 4096;                            \
    const u16* hB = smem + (d) * 16384 + 8192 + (s) * 4096;                     \
    bf16x8 av[4], bv[4];                                                        \
    _Pragma("unroll")                                                           \
    for (int m_ = 0; m_ < 4; ++m_)                                              \
      av[m_] = *reinterpret_cast<const bf16x8*>(hA + aoff[m_]);                 \
    _Pragma("unroll")                                                           \
    for (int n_ = 0; n_ < 4; ++n_)                                              \
      bv[n_] = *reinterpret_cast<const bf16x8*>(hB + boff[n_]);                 \
    STGSTMT;                                                                    \
    asm volatile("s_waitcnt vmcnt(4)" ::: "memory");                            \
    __builtin_amdgcn_s_barrier();                                               \
    asm volatile("" ::: "memory");                                              \
    __builtin_amdgcn_s_setprio(1);                                              \
    _Pragma("unroll")                                                           \
    for (int m_ = 0; m_ < 4; ++m_)                                              \
      _Pragma("unroll")                                                         \
      for (int n_ = 0; n_ < 4; ++n_)                                            \
        acc[m_][n_] = __builtin_amdgcn_mfma_f32_16x16x32_bf16(                  \
            av[m_], bv[n_], acc[m_][n_], 0, 0, 0);                              \
    __builtin_amdgcn_s_setprio(0);                                              \
    asm volatile("" ::: "memory");                                              \
  } while (0)

#pragma unroll 1
  for (int i = 0; i < NTILE / 2; ++i) {
    const int t1 = 2 * i + 1;
    const int t2 = (2 * i + 2 < NTILE) ? 2 * i + 2 : NTILE - 1;
    PHASE(0, 0, STGH(t1, 0, 16384));
    PHASE(0, 1, STGH(t1, 1, 16384));
    PHASE(1, 0, STGH(t2, 0, 0));
    PHASE(1, 1, STGH(t2, 1, 0));
  }
#undef PHASE
#undef STGH

  // ---- epilogue: C map col=lane&15, row=(lane>>4)*4+q ----
  if constexpr (EPI == 2) {            // bf16, scaled, causal mask (scores)
    u16* C = (u16*)Cv + (long)z * sC;
#pragma unroll
    for (int n = 0; n < 4; ++n) {
      const int col = bn + wc * 64 + n * 16 + lr;
#pragma unroll
      for (int m = 0; m < 4; ++m) {
        const int row0 = bm + wr * 64 + m * 16 + kg * 4;
#pragma unroll
        for (int q = 0; q < 4; ++q) {
          const int row = row0 + q;
          float v = acc[m][n][q] * scale;
          if (col > row) v = -1e30f;
          C[(long)row * N + col] = f2bf(v);
        }
      }
    }
  } else {                             // EPI 4: fused QKV routing (proj)
    constexpr long M = (long)NB * S_LEN;
    const int sel = bn >> 10;          // 0=Q, 1=K, 2=V (block-uniform, 128 | 1024)
    const float* bias = (sel == 0) ? b0 : (sel == 1) ? b1 : b2;
    u16* QK = (u16*)Cv;
#pragma unroll
    for (int n = 0; n < 4; ++n) {
      const int col = bn + wc * 64 + n * 16 + lr;
      const int h   = col & (HID - 1);
      const float bbv = bias[h];
#pragma unroll
      for (int m = 0; m < 4; ++m) {
        const int row0 = bm + wr * 64 + m * 16 + kg * 4;
        if (sel < 2) {
          u16* dst = QK + (long)sel * M * HID + (long)row0 * HID + h;
#pragma unroll
          for (int q = 0; q < 4; ++q)
            dst[(long)q * HID] = f2bf(acc[m][n][q] + bbv);
        } else {
          const int b = row0 >> 11;
          const int s = row0 & (S_LEN - 1);
          ushort4 o = make_ushort4(f2bf(acc[m][n][0] + bbv), f2bf(acc[m][n][1] + bbv),
                                   f2bf(acc[m][n][2] + bbv), f2bf(acc[m][n][3] + bbv));
          *reinterpret_cast<ushort4*>(VT + ((long)b * HID + h) * S_LEN + s) = o;
        }
      }
    }
  }
}

// ============================================================================
// gemm_pv: load-balanced causal PV (R10-proven, unchanged).
// ============================================================================

__global__ __launch_bounds__(512, 2)
void gemm_pv(const u16* __restrict__ Pm, const u16* __restrict__ VTm, float* __restrict__ Cm)
{
  const int z = blockIdx.z;
  const u16* A = Pm  + (long)z * S_LEN * S_LEN;
  const u16* B = VTm + (long)z * HID * S_LEN;
  float*    Cz = Cm  + (long)z * S_LEN * HID;

  __shared__ __align__(16) u16 smem[32768];   // 64 KB

  const int tid = threadIdx.x;
  const int l   = tid & 63;
  const int w   = tid >> 6;
  const int wr  = w >> 2;              // 0..1 (64-row)
  const int wc  = w & 3;               // 0..3 (32-col)
  const int bn  = blockIdx.x * 128;
  const int pr  = blockIdx.y;          // 0..7

  const int lr  = l & 15;
  const int kg  = l >> 4;
  const int kgp = kg ^ (((lr >> 3) & 1) << 1);
  int aoff[4], boff[2];
#pragma unroll
  for (int m = 0; m < 4; ++m) aoff[m] = (wr * 64 + m * 16 + lr) * 32 + kgp * 8;
#pragma unroll
  for (int n = 0; n < 2; ++n) boff[n] = (wc * 32 + n * 16 + lr) * 32 + kgp * 8;

  const int arow = w * 16 + (l >> 2);                 // 0..127
  const int acs  = (l & 3) ^ (((l >> 5) & 1) << 1);

#pragma unroll 1
  for (int it = 0; it < 2; ++it) {
    const int bi = (it == 0) ? (15 - pr) : pr;        // long row-tile first
    const int bm = bi * 128;
    const int NTILE = (bi + 1) * 2;                   // even, >= 2

    const u16* gbA = A + (long)(bm + arow) * S_LEN + acs * 8;
    const u16* gbB = B + (long)(bn + arow) * S_LEN + acs * 8;

#define STGH(t, s, dbase)                                                       \
  do {                                                                          \
    const long _o = (long)(t) * 64 + (s) * 32;                                  \
    gld_lds16(gbA + _o, smem + (dbase) + (s) * 4096 + w * 512);                 \
    gld_lds16(gbB + _o, smem + (dbase) + 8192 + (s) * 4096 + w * 512);          \
  } while (0)

    if (it) {                          // all iter-1 LDS reads complete past here
      __builtin_amdgcn_s_barrier();
      asm volatile("" ::: "memory");
    }

    f32x4 acc[4][2] = {};

    // prologue: tile 0 both halves -> buf0; drain
    STGH(0, 0, 0);
    STGH(0, 1, 0);
    asm volatile("s_waitcnt vmcnt(0)" ::: "memory");
    __builtin_amdgcn_s_barrier();
    asm volatile("" ::: "memory");

#define PHASE(d, s, STGSTMT)                                                    \
  do {                                                                          \
    const u16* hA = smem + (d) * 16384 + (s) * 4096;                            \
    const u16* hB = smem + (d) * 16384 + 8192 + (s) * 4096;                     \
    bf16x8 av[4], bv[2];                                                        \
    _Pragma("unroll")                                                           \
    for (int m_ = 0; m_ < 4; ++m_)                                              \
      av[m_] = *reinterpret_cast<const bf16x8*>(hA + aoff[m_]);                 \
    _Pragma("unroll")                                                           \
    for (int n_ = 0; n_ < 2; ++n_)                                              \
      bv[n_] = *reinterpret_cast<const bf16x8*>(hB + boff[n_]);                 \
    STGSTMT;                                                                    \
    asm volatile("s_waitcnt vmcnt(2)" ::: "memory");                            \
    __builtin_amdgcn_s_barrier();                                               \
    asm volatile("" ::: "memory");                                              \
    __builtin_amdgcn_s_setprio(1);                                              \
    _Pragma("unroll")                                                           \
    for (int m_ = 0; m_ < 4; ++m_)                                              \
      _Pragma("unroll")                                                         \
      for (int n_ = 0; n_ < 2; ++n_)                                            \
        acc[m_][n_] = __builtin_amdgcn_mfma_f32_16x16x32_bf16(                  \
            av[m_], bv[n_], acc[m_][n_], 0, 0, 0);                              \
    __builtin_amdgcn_s_setprio(0);                                              \
    asm volatile("" ::: "memory");                                              \
  } while (0)

#pragma unroll 1
    for (int i = 0; i < NTILE / 2; ++i) {
      const int t1 = 2 * i + 1;
      const int t2 = (2 * i + 2 < NTILE) ? 2 * i + 2 : NTILE - 1;
      PHASE(0, 0, STGH(t1, 0, 16384));
      PHASE(0, 1, STGH(t1, 1, 16384));
      PHASE(1, 0, STGH(t2, 0, 0));
      PHASE(1, 1, STGH(t2, 1, 0));
    }
#undef PHASE
#undef STGH

    // epilogue: C map col=lane&15, row=(lane>>4)*4+q
#pragma unroll
    for (int n = 0; n < 2; ++n) {
      const int col = bn + wc * 32 + n * 16 + lr;
#pragma unroll
      for (int m = 0; m < 4; ++m) {
        const int row0 = bm + wr * 64 + m * 16 + kg * 4;
#pragma unroll
        for (int q = 0; q < 4; ++q)
          Cz[(long)(row0 + q) * HID + col] = acc[m][n][q];
      }
    }
  }
}

// ---------- causal row softmax: bf16 scores -> bf16 P (kend 128-aligned) ----------
// 256 threads/row; each thread handles 8 bf16 = one 16B uint4 load/store.

__global__ __launch_bounds__(256)
void softmax_causal(const u16* __restrict__ Sc, u16* __restrict__ P, long sS, long sP)
{
  const int row  = blockIdx.x;
  const int z    = blockIdx.y;
  const int kend = ((row >> 7) + 1) << 7;
  const u16* srow = Sc + (long)z * sS + (long)row * S_LEN;
  u16*      prow = P  + (long)z * sP + (long)row * S_LEN;
  const int t = threadIdx.x;
  const int lane = t & 63, wave = t >> 6;

  const bool p0 = (8 * t) < kend;      // kend % 128 == 0 -> all-8 valid or none

  float e[8];
  float mx = -1e30f;
  if (p0) {
    uint4 u = reinterpret_cast<const uint4*>(srow)[t];
    uint32_t wv[4] = {u.x, u.y, u.z, u.w};
#pragma unroll
    for (int i = 0; i < 4; ++i) {
      const float lo = bf2f((wv[i] & 0xffffu) << 16);
      const float hi = bf2f(wv[i] & 0xffff0000u);
      e[2 * i]     = lo;
      e[2 * i + 1] = hi;
      mx = fmaxf(mx, fmaxf(lo, hi));
    }
  }

  __shared__ float red[8];
#pragma unroll
  for (int off = 32; off; off >>= 1) mx = fmaxf(mx, __shfl_down(mx, off));
  if (lane == 0) red[wave] = mx;
  __syncthreads();
  mx = fmaxf(fmaxf(red[0], red[1]), fmaxf(red[2], red[3]));

  float sm = 0.0f;
  if (p0) {
#pragma unroll
    for (int i = 0; i < 8; ++i) e[i] = __expf(e[i] - mx);
    sm = ((e[0] + e[1]) + (e[2] + e[3])) + ((e[4] + e[5]) + (e[6] + e[7]));
  }
#pragma unroll
  for (int off = 32; off; off >>= 1) sm += __shfl_down(sm, off);
  if (lane == 0) red[4 + wave] = sm;
  __syncthreads();
  sm = (red[4] + red[5]) + (red[6] + red[7]);

  const float inv = 1.0f / sm;
  if (p0) {
    uint32_t o[4];
#pragma unroll
    for (int i = 0; i < 4; ++i) {
      const uint32_t a = f2bf(e[2 * i] * inv);
      const uint32_t b = f2bf(e[2 * i + 1] * inv);
      o[i] = a | (b << 16);
    }
    reinterpret_cast<uint4*>(prow)[t] = make_uint4(o[0], o[1], o[2], o[3]);
  }
}

// ---------- launch ----------

extern "C" void kernel_launch(void* const* d_in, const int* in_sizes, int n_in,
                              void* d_out, int out_size, void* d_ws, size_t ws_size,
                              hipStream_t stream)
{
  const float* x  = (const float*)d_in[0];
  const float* Wq = (const float*)d_in[1];
  const float* bq = (const float*)d_in[2];
  const float* Wk = (const float*)d_in[3];
  const float* bk = (const float*)d_in[4];
  const float* Wv = (const float*)d_in[5];
  const float* bv = (const float*)d_in[6];
  float* out = (float*)d_out;

  const long M = (long)NB * S_LEN;  // 8192

  u16* xb  = (u16*)d_ws;
  u16* wqb = xb  + M * EMB;         // wq/wk/wv contiguous -> fused [3072,1024]
  u16* Qb  = wqb + 3L * HID * EMB;  // Q then K contiguous
  u16* Kb  = Qb  + M * HID;
  u16* VT  = Kb  + M * HID;
  char* rest = (char*)(VT + M * HID);
  const size_t used  = (size_t)(rest - (char*)d_ws);
  const size_t ssz   = (size_t)S_LEN * S_LEN;
  const size_t need4 = used + (size_t)NB * ssz * 2 * 2;   // bf16 scores + bf16 P
  const int nb = (ws_size >= need4) ? NB : 1;
  u16* scores = (u16*)rest;
  u16* P      = scores + (size_t)nb * ssz;

  // fp32 -> bf16 (single fused launch; nw4 = 1024*1024/4 = 2^18)
  cvt_all<<<2048, 256, 0, stream>>>(x, Wq, Wk, Wv, xb, wqb, (int)(M * EMB / 4), 18);

  // fused QKV projection: 128x128 4-wave template, grid 1536 = 3 exact rounds
  gemmT<4><<<dim3(24, 64, 1), 256, 0, stream>>>(xb, wqb, Qb, bq, bk, bv, VT,
                                                3 * HID, 0, 0, 0, 1.0f);

  const float scale = 0.03125f;  // 1/sqrt(1024)
  const int TRI = 16 * 17 / 2;   // 136 lower-tri 128x128 blocks

  if (nb == NB) {
    dim3 gs(TRI, 1, NB);
    gemmT<2><<<gs, 256, 0, stream>>>(Qb, Kb, scores, nullptr, nullptr, nullptr, nullptr,
                                     S_LEN, (long)S_LEN * HID, (long)S_LEN * HID,
                                     (long)ssz, scale);
    softmax_causal<<<dim3(S_LEN, NB), 256, 0, stream>>>(scores, P, (long)ssz, (long)ssz);
    gemm_pv<<<dim3(8, 8, NB), 512, 0, stream>>>(P, VT, out);
  } else {
    for (int b = 0; b < NB; ++b) {
      const u16* Qbb = Qb + (long)b * S_LEN * HID;
      const u16* Kbb = Kb + (long)b * S_LEN * HID;
      const u16* VTb = VT + (long)b * HID * S_LEN;
      float* outb = out + (long)b * S_LEN * HID;
      dim3 gs(TRI, 1, 1);
      gemmT<2><<<gs, 256, 0, stream>>>(Qbb, Kbb, scores, nullptr, nullptr, nullptr, nullptr,
                                       S_LEN, 0, 0, 0, scale);
      softmax_causal<<<dim3(S_LEN, 1), 256, 0, stream>>>(scores, P, 0, 0);
      gemm_pv<<<dim3(8, 8, 1), 512, 0, stream>>>(P, VTb, outb);
    }
  }
}